// Round 1
// baseline (19742.015 us; speedup 1.0000x reference)
//
#include <hip/hip_runtime.h>
#include <hip/hip_bf16.h>
#include <math.h>

#define L_ 6
#define C_ 768
#define H_ 12
#define T_ 1024
#define B_ 8
#define V_ 50257
#define DH_ 64
#define C3_ 2304
#define C4_ 3072
#define BT_ 8192

__device__ __forceinline__ float wred_sum(float v) {
#pragma unroll
    for (int m = 32; m >= 1; m >>= 1) v += __shfl_xor(v, m, 64);
    return v;
}

// ---------------- embedding: x = wte[idx] + wpe ----------------
__global__ __launch_bounds__(256) void embed_kernel(const int* __restrict__ idx,
                                                    const float* __restrict__ wte,
                                                    const float* __restrict__ wpe,
                                                    float* __restrict__ x) {
    int c = blockIdx.x * 256 + threadIdx.x;   // grid.x = 3
    int token = blockIdx.y;                   // grid.y = BT
    int t = token & (T_ - 1);
    int tok = idx[token];
    x[(size_t)token * C_ + c] = wte[(size_t)tok * C_ + c] + wpe[(size_t)t * C_ + c];
}

// ---------------- layernorm: one block per row (C=768=3*256) ----------------
__global__ __launch_bounds__(256) void ln_kernel(const float* __restrict__ in,
                                                 const float* __restrict__ w,
                                                 const float* __restrict__ bb,
                                                 float* __restrict__ out,
                                                 int rstride, int roff) {
    int row = blockIdx.x;
    size_t base = (size_t)(row * rstride + roff) * C_;
    int tid = threadIdx.x;
    int lane = tid & 63, wave = tid >> 6;
    float v0 = in[base + tid];
    float v1 = in[base + tid + 256];
    float v2 = in[base + tid + 512];
    __shared__ float red[4];
    float s = wred_sum(v0 + v1 + v2);
    if (lane == 0) red[wave] = s;
    __syncthreads();
    float mean = (red[0] + red[1] + red[2] + red[3]) * (1.0f / 768.0f);
    __syncthreads();
    float d0 = v0 - mean, d1 = v1 - mean, d2 = v2 - mean;
    float q = wred_sum(d0 * d0 + d1 * d1 + d2 * d2);
    if (lane == 0) red[wave] = q;
    __syncthreads();
    float var = (red[0] + red[1] + red[2] + red[3]) * (1.0f / 768.0f);
    float rstd = rsqrtf(var + 1e-5f);
    size_t ob = (size_t)row * C_;
    out[ob + tid]       = d0 * rstd * w[tid]       + bb[tid];
    out[ob + tid + 256] = d1 * rstd * w[tid + 256] + bb[tid + 256];
    out[ob + tid + 512] = d2 * rstd * w[tid + 512] + bb[tid + 512];
}

// ---------------- generic f32 GEMM: out = act(A[M,K] @ W[N,K]^T + bias) (+resid) ----------------
template <int GELU, int RESID>
__global__ __launch_bounds__(256) void gemm_bt(const float* __restrict__ A,
                                               const float* __restrict__ W,
                                               const float* __restrict__ bias,
                                               const float* __restrict__ resid,
                                               float* __restrict__ out,
                                               int M, int N, int K) {
    __shared__ float As[64][33];
    __shared__ float Ws[64][33];
    const int tid = threadIdx.x;
    const int tx = tid & 15, ty = tid >> 4;
    const int m0 = blockIdx.y * 64, n0 = blockIdx.x * 64;
    const int kcol = tid & 31;
    const int rseg = tid >> 5;
    float acc[4][4] = {};
    for (int kt = 0; kt < K; kt += 32) {
#pragma unroll
        for (int p = 0; p < 8; ++p) {
            int r = rseg + p * 8;
            As[r][kcol] = A[(size_t)(m0 + r) * K + kt + kcol];
            Ws[r][kcol] = W[(size_t)(n0 + r) * K + kt + kcol];
        }
        __syncthreads();
#pragma unroll
        for (int kk = 0; kk < 32; ++kk) {
            float a[4], b[4];
#pragma unroll
            for (int i = 0; i < 4; ++i) a[i] = As[ty * 4 + i][kk];
#pragma unroll
            for (int j = 0; j < 4; ++j) b[j] = Ws[tx * 4 + j][kk];
#pragma unroll
            for (int i = 0; i < 4; ++i)
#pragma unroll
                for (int j = 0; j < 4; ++j) acc[i][j] += a[i] * b[j];
        }
        __syncthreads();
    }
#pragma unroll
    for (int i = 0; i < 4; ++i) {
        int mrow = m0 + ty * 4 + i;
#pragma unroll
        for (int j = 0; j < 4; ++j) {
            int ncol = n0 + tx * 4 + j;
            float c = acc[i][j] + bias[ncol];
            if (GELU) c = 0.5f * c * (1.0f + erff(c * 0.70710678118654752f));
            if (RESID) c += resid[(size_t)mrow * N + ncol];
            out[(size_t)mrow * N + ncol] = c;
        }
    }
}

// ---------------- attention with LIF gating ----------------
// grid: (T/8, B*H), block 256. Each wave owns 2 q-rows.
__global__ __launch_bounds__(256) void attn_kernel(const float* __restrict__ qkv,
                                                   const float* __restrict__ thr,
                                                   const float* __restrict__ leak,
                                                   const float* __restrict__ steep,
                                                   float* __restrict__ y) {
    __shared__ float qs[8][64];
    __shared__ float KV[64][65];
    __shared__ float mods[8][1024];
    const int tid = threadIdx.x;
    const int lane = tid & 63, wave = tid >> 6;
    const int bh = blockIdx.y;
    const int b = bh / H_, hh = bh % H_;
    const int qbase = blockIdx.x * 8;

    // load q rows (each wave its own 2 rows)
#pragma unroll
    for (int rr = 0; rr < 2; ++rr) {
        int r = wave * 2 + rr;
        qs[r][lane] = qkv[(size_t)(b * T_ + qbase + r) * C3_ + hh * DH_ + lane];
    }
    float th = fabsf(thr[hh]) * 0.1f;
    float lk = 1.0f / (1.0f + expf(-leak[hh]));
    float stv = steep[hh];
    float st = (stv > 15.0f) ? stv : log1pf(expf(stv));

    float sc[2][16];
#pragma unroll
    for (int rr = 0; rr < 2; ++rr)
#pragma unroll
        for (int t = 0; t < 16; ++t) sc[rr][t] = -1e30f;

    const int ntiles = (qbase + 8 + 63) >> 6;

    // ---- scores: QK^T with causal mask ----
    for (int tile = 0; tile < ntiles; ++tile) {
        const int kt0 = tile << 6;
        __syncthreads();
#pragma unroll
        for (int p = 0; p < 16; ++p) {
            int i2 = p * 256 + tid;
            int r = i2 >> 6, d = i2 & 63;
            KV[r][d] = qkv[(size_t)(b * T_ + kt0 + r) * C3_ + C_ + hh * DH_ + d];
        }
        __syncthreads();
        int k = kt0 + lane;
#pragma unroll
        for (int rr = 0; rr < 2; ++rr) {
            int row = wave * 2 + rr;
            int q0 = qbase + row;
            if (k <= q0) {
                float s = 0.0f;
#pragma unroll
                for (int d = 0; d < 64; ++d) s += qs[row][d] * KV[lane][d];
                sc[rr][tile] = s * 0.125f;
            }
        }
    }

    // ---- softmax + LIF gate + renorm (wave-parallel, 64 lanes active) ----
#pragma unroll
    for (int rr = 0; rr < 2; ++rr) {
        int row = wave * 2 + rr;
        float mx = -1e30f;
#pragma unroll
        for (int t = 0; t < 16; ++t) mx = fmaxf(mx, sc[rr][t]);
#pragma unroll
        for (int m2 = 32; m2 >= 1; m2 >>= 1) mx = fmaxf(mx, __shfl_xor(mx, m2, 64));
        float p[16];
        float psum = 0.0f;
#pragma unroll
        for (int t = 0; t < 16; ++t) {
            float pv = (sc[rr][t] > -1e29f) ? expf(sc[rr][t] - mx) : 0.0f;
            p[t] = pv;
            psum += pv;
        }
        psum = wred_sum(psum);
        float inv = 1.0f / psum;
        float msum = 0.0f;
#pragma unroll
        for (int t = 0; t < 16; ++t) {
            float pp = p[t] * inv;
            float fire = 1.0f / (1.0f + expf(-st * (pp - th)));
            float wgt = fire + lk * (1.0f - fire);
            float md = pp * wgt;
            p[t] = md;
            msum += md;
        }
        msum = wred_sum(msum);
        float inv2 = 1.0f / (msum + 1e-8f);
#pragma unroll
        for (int t = 0; t < 16; ++t) mods[row][t * 64 + lane] = p[t] * inv2;
    }

    // ---- PV ----
    float acc[2] = {0.0f, 0.0f};
    __syncthreads();
    for (int tile = 0; tile < ntiles; ++tile) {
        const int kt0 = tile << 6;
#pragma unroll
        for (int p2 = 0; p2 < 16; ++p2) {
            int i2 = p2 * 256 + tid;
            int r = i2 >> 6, d = i2 & 63;
            KV[r][d] = qkv[(size_t)(b * T_ + kt0 + r) * C3_ + 2 * C_ + hh * DH_ + d];
        }
        __syncthreads();
#pragma unroll
        for (int rr = 0; rr < 2; ++rr) {
            int row = wave * 2 + rr;
            int q0 = qbase + row;
            int kmax = q0 - kt0;
            if (kmax > 63) kmax = 63;
            for (int r2 = 0; r2 <= kmax; ++r2)
                acc[rr] += mods[row][kt0 + r2] * KV[r2][lane];
        }
        __syncthreads();
    }
#pragma unroll
    for (int rr = 0; rr < 2; ++rr) {
        int q0 = qbase + wave * 2 + rr;
        y[(size_t)(b * T_ + q0) * C_ + hh * DH_ + lane] = acc[rr];
    }
}

// ---------------- tied LM head: out[b,v] = sum_c xf[b,c]*wte[v,c] ----------------
__global__ __launch_bounds__(256) void logits_kernel(const float* __restrict__ xf,
                                                     const float* __restrict__ wte,
                                                     float* __restrict__ out) {
    __shared__ float xs[8 * 768];
    int tid = threadIdx.x;
#pragma unroll
    for (int p = 0; p < 24; ++p) xs[p * 256 + tid] = xf[p * 256 + tid];
    __syncthreads();
    int lane = tid & 63, wave = tid >> 6;
    int v = blockIdx.x * 4 + wave;
    if (v < V_) {
        float acc[8] = {};
        for (int cc = lane; cc < 768; cc += 64) {
            float wv = wte[(size_t)v * C_ + cc];
#pragma unroll
            for (int b2 = 0; b2 < 8; ++b2) acc[b2] += wv * xs[b2 * 768 + cc];
        }
#pragma unroll
        for (int b2 = 0; b2 < 8; ++b2) {
            float r = wred_sum(acc[b2]);
            if (lane == 0) out[(size_t)b2 * V_ + v] = r;
        }
    }
}

extern "C" void kernel_launch(void* const* d_in, const int* in_sizes, int n_in,
                              void* d_out, int out_size, void* d_ws, size_t ws_size,
                              hipStream_t stream) {
    (void)in_sizes; (void)n_in; (void)out_size; (void)ws_size;
    const int*   idx     = (const int*)d_in[0];
    const float* wte     = (const float*)d_in[1];
    const float* wpe     = (const float*)d_in[2];
    const float* ln1_w   = (const float*)d_in[3];
    const float* ln1_b   = (const float*)d_in[4];
    const float* attn_w  = (const float*)d_in[5];
    const float* attn_b  = (const float*)d_in[6];
    const float* proj_w  = (const float*)d_in[7];
    const float* proj_b  = (const float*)d_in[8];
    const float* thr     = (const float*)d_in[9];
    const float* leak    = (const float*)d_in[10];
    const float* steep   = (const float*)d_in[11];
    const float* ln2_w   = (const float*)d_in[12];
    const float* ln2_b   = (const float*)d_in[13];
    const float* fc_w    = (const float*)d_in[14];
    const float* fc_b    = (const float*)d_in[15];
    const float* mproj_w = (const float*)d_in[16];
    const float* mproj_b = (const float*)d_in[17];
    const float* lnf_w   = (const float*)d_in[18];
    const float* lnf_b   = (const float*)d_in[19];
    float* out = (float*)d_out;

    float* ws  = (float*)d_ws;
    float* x   = ws;
    float* h   = x + (size_t)BT_ * C_;
    float* qkv = h + (size_t)BT_ * C_;
    float* y   = qkv + (size_t)BT_ * C3_;
    float* m   = y + (size_t)BT_ * C_;
    float* xf  = m + (size_t)BT_ * C4_;

    embed_kernel<<<dim3(3, BT_), 256, 0, stream>>>(idx, wte, wpe, x);

    for (int l = 0; l < L_; ++l) {
        ln_kernel<<<BT_, 256, 0, stream>>>(x, ln1_w + l * C_, ln1_b + l * C_, h, 1, 0);
        gemm_bt<0, 0><<<dim3(C3_ / 64, BT_ / 64), 256, 0, stream>>>(
            h, attn_w + (size_t)l * C3_ * C_, attn_b + l * C3_, nullptr, qkv, BT_, C3_, C_);
        attn_kernel<<<dim3(T_ / 8, B_ * H_), 256, 0, stream>>>(
            qkv, thr + l * H_, leak + l * H_, steep + l * H_, y);
        gemm_bt<0, 1><<<dim3(C_ / 64, BT_ / 64), 256, 0, stream>>>(
            y, proj_w + (size_t)l * C_ * C_, proj_b + l * C_, x, x, BT_, C_, C_);
        ln_kernel<<<BT_, 256, 0, stream>>>(x, ln2_w + l * C_, ln2_b + l * C_, h, 1, 0);
        gemm_bt<1, 0><<<dim3(C4_ / 64, BT_ / 64), 256, 0, stream>>>(
            h, fc_w + (size_t)l * C4_ * C_, fc_b + l * C4_, nullptr, m, BT_, C4_, C_);
        gemm_bt<0, 1><<<dim3(C_ / 64, BT_ / 64), 256, 0, stream>>>(
            m, mproj_w + (size_t)l * C_ * C4_, mproj_b + l * C_, x, x, BT_, C_, C4_);
    }

    ln_kernel<<<8, 256, 0, stream>>>(x, lnf_w, lnf_b, xf, T_, T_ - 1);
    logits_kernel<<<(V_ + 3) / 4, 256, 0, stream>>>(xf, wte, out);
}

// Round 2
// 7575.002 us; speedup vs baseline: 2.6062x; 2.6062x over previous
//
#include <hip/hip_runtime.h>
#include <hip/hip_bf16.h>
#include <math.h>

#define L_ 6
#define C_ 768
#define H_ 12
#define T_ 1024
#define B_ 8
#define V_ 50257
#define DH_ 64
#define C3_ 2304
#define C4_ 3072
#define BT_ 8192

typedef __attribute__((ext_vector_type(8))) short short8;
typedef __attribute__((ext_vector_type(4))) float f32x4;

__device__ __forceinline__ float wred_sum(float v) {
#pragma unroll
    for (int m = 32; m >= 1; m >>= 1) v += __shfl_xor(v, m, 64);
    return v;
}

__device__ __forceinline__ unsigned short f2bf(float f) {
    unsigned u = __builtin_bit_cast(unsigned, f);
    u += 0x7fffu + ((u >> 16) & 1u);   // round-to-nearest-even
    return (unsigned short)(u >> 16);
}

// ---------------- f32 -> bf16 bulk convert (weights) ----------------
__global__ __launch_bounds__(256) void cvt_bf16(const float* __restrict__ in,
                                                unsigned short* __restrict__ out) {
    size_t i = ((size_t)blockIdx.x * 256 + threadIdx.x) * 4;
    float4 v = *(const float4*)(in + i);
    ushort4 o;
    o.x = f2bf(v.x); o.y = f2bf(v.y); o.z = f2bf(v.z); o.w = f2bf(v.w);
    *(ushort4*)(out + i) = o;
}

// ---------------- embedding: x = wte[idx] + wpe ----------------
__global__ __launch_bounds__(256) void embed_kernel(const int* __restrict__ idx,
                                                    const float* __restrict__ wte,
                                                    const float* __restrict__ wpe,
                                                    float* __restrict__ x) {
    int c = blockIdx.x * 256 + threadIdx.x;
    int token = blockIdx.y;
    int t = token & (T_ - 1);
    int tok = idx[token];
    x[(size_t)token * C_ + c] = wte[(size_t)tok * C_ + c] + wpe[(size_t)t * C_ + c];
}

// ---------------- layernorm (f32 in, f32 or bf16 out) ----------------
template <int OBF>
__global__ __launch_bounds__(256) void ln_kernel(const float* __restrict__ in,
                                                 const float* __restrict__ w,
                                                 const float* __restrict__ bb,
                                                 void* __restrict__ outp,
                                                 int rstride, int roff) {
    int row = blockIdx.x;
    size_t base = (size_t)(row * rstride + roff) * C_;
    int tid = threadIdx.x;
    int lane = tid & 63, wave = tid >> 6;
    float v0 = in[base + tid];
    float v1 = in[base + tid + 256];
    float v2 = in[base + tid + 512];
    __shared__ float red[4];
    float s = wred_sum(v0 + v1 + v2);
    if (lane == 0) red[wave] = s;
    __syncthreads();
    float mean = (red[0] + red[1] + red[2] + red[3]) * (1.0f / 768.0f);
    __syncthreads();
    float d0 = v0 - mean, d1 = v1 - mean, d2 = v2 - mean;
    float q = wred_sum(d0 * d0 + d1 * d1 + d2 * d2);
    if (lane == 0) red[wave] = q;
    __syncthreads();
    float var = (red[0] + red[1] + red[2] + red[3]) * (1.0f / 768.0f);
    float rstd = rsqrtf(var + 1e-5f);
    size_t ob = (size_t)row * C_;
    float o0 = d0 * rstd * w[tid] + bb[tid];
    float o1 = d1 * rstd * w[tid + 256] + bb[tid + 256];
    float o2 = d2 * rstd * w[tid + 512] + bb[tid + 512];
    if (OBF) {
        unsigned short* out = (unsigned short*)outp;
        out[ob + tid] = f2bf(o0); out[ob + tid + 256] = f2bf(o1); out[ob + tid + 512] = f2bf(o2);
    } else {
        float* out = (float*)outp;
        out[ob + tid] = o0; out[ob + tid + 256] = o1; out[ob + tid + 512] = o2;
    }
}

// ---------------- bf16 MFMA GEMM (m97 structure): out = act(A[M,K] @ W[N,K]^T + b) ----------------
// 128x128 tile, BK=32, 256 threads = 4 waves (2x2), each wave 64x64 via 4x4 mfma_16x16x32 frags.
template <int GELU, int RESID, int OUT_BF16>
__global__ __launch_bounds__(256) void gemm_mfma(const unsigned short* __restrict__ A,
                                                 const unsigned short* __restrict__ W,
                                                 const float* __restrict__ bias,
                                                 const float* __restrict__ resid,
                                                 void* __restrict__ outp,
                                                 int M, int N, int K) {
    __shared__ __align__(16) short As[128 * 32];
    __shared__ __align__(16) short Bs[128 * 32];
    const int tid = threadIdx.x;
    const int lane = tid & 63, wave = tid >> 6;
    const int m0 = blockIdx.y * 128, n0 = blockIdx.x * 128;
    const int wr = wave >> 1, wc = wave & 1;
    f32x4 acc[4][4] = {};

    const int srow = lane >> 2;          // row within 16-row chunk
    const int scolb = (lane & 3) * 16;   // byte offset within 64B row

    for (int kt = 0; kt < K; kt += 32) {
#pragma unroll
        for (int i = 0; i < 2; ++i) {
            int chunk = wave * 2 + i;    // 0..7 -> rows chunk*16..+15
            int row = chunk * 16 + srow;
            const char* gA = (const char*)(A + (size_t)(m0 + row) * K + kt) + scolb;
            const char* gB = (const char*)(W + (size_t)(n0 + row) * K + kt) + scolb;
            __builtin_amdgcn_global_load_lds(
                (const __attribute__((address_space(1))) void*)gA,
                (__attribute__((address_space(3))) void*)((char*)As + chunk * 1024 + lane * 16),
                16, 0, 0);
            __builtin_amdgcn_global_load_lds(
                (const __attribute__((address_space(1))) void*)gB,
                (__attribute__((address_space(3))) void*)((char*)Bs + chunk * 1024 + lane * 16),
                16, 0, 0);
        }
        __syncthreads();
        const int fr = lane & 15, kq = lane >> 4;
        short8 a[4], b[4];
#pragma unroll
        for (int m = 0; m < 4; ++m)
            a[m] = *(const short8*)(&As[(wr * 64 + m * 16 + fr) * 32 + kq * 8]);
#pragma unroll
        for (int n = 0; n < 4; ++n)
            b[n] = *(const short8*)(&Bs[(wc * 64 + n * 16 + fr) * 32 + kq * 8]);
#pragma unroll
        for (int m = 0; m < 4; ++m)
#pragma unroll
            for (int n = 0; n < 4; ++n)
                acc[m][n] = __builtin_amdgcn_mfma_f32_16x16x32_bf16(a[m], b[n], acc[m][n], 0, 0, 0);
        __syncthreads();
    }

    const int fr = lane & 15, rq = lane >> 4;
#pragma unroll
    for (int m = 0; m < 4; ++m) {
        int rbase = m0 + wr * 64 + m * 16 + rq * 4;
#pragma unroll
        for (int n = 0; n < 4; ++n) {
            int col = n0 + wc * 64 + n * 16 + fr;
            float bv = bias[col];
#pragma unroll
            for (int j = 0; j < 4; ++j) {
                int row = rbase + j;
                float c = acc[m][n][j] + bv;
                if (GELU) c = 0.5f * c * (1.0f + erff(c * 0.70710678118654752f));
                if (RESID) c += resid[(size_t)row * N + col];
                if (OUT_BF16)
                    ((unsigned short*)outp)[(size_t)row * N + col] = f2bf(c);
                else
                    ((float*)outp)[(size_t)row * N + col] = c;
            }
        }
    }
}

// ---------------- attention with LIF gating (f32 qkv in, bf16 y out) ----------------
__global__ __launch_bounds__(256) void attn_kernel(const float* __restrict__ qkv,
                                                   const float* __restrict__ thr,
                                                   const float* __restrict__ leak,
                                                   const float* __restrict__ steep,
                                                   unsigned short* __restrict__ y) {
    __shared__ float qs[8][64];
    __shared__ float KV[64][65];
    __shared__ float mods[8][1024];
    const int tid = threadIdx.x;
    const int lane = tid & 63, wave = tid >> 6;
    const int bh = blockIdx.y;
    const int b = bh / H_, hh = bh % H_;
    const int qbase = blockIdx.x * 8;

#pragma unroll
    for (int rr = 0; rr < 2; ++rr) {
        int r = wave * 2 + rr;
        qs[r][lane] = qkv[(size_t)(b * T_ + qbase + r) * C3_ + hh * DH_ + lane];
    }
    float th = fabsf(thr[hh]) * 0.1f;
    float lk = 1.0f / (1.0f + expf(-leak[hh]));
    float stv = steep[hh];
    float st = (stv > 15.0f) ? stv : log1pf(expf(stv));

    float sc[2][16];
#pragma unroll
    for (int rr = 0; rr < 2; ++rr)
#pragma unroll
        for (int t = 0; t < 16; ++t) sc[rr][t] = -1e30f;

    const int ntiles = (qbase + 8 + 63) >> 6;

    for (int tile = 0; tile < ntiles; ++tile) {
        const int kt0 = tile << 6;
        __syncthreads();
#pragma unroll
        for (int p = 0; p < 16; ++p) {
            int i2 = p * 256 + tid;
            int r = i2 >> 6, d = i2 & 63;
            KV[r][d] = qkv[(size_t)(b * T_ + kt0 + r) * C3_ + C_ + hh * DH_ + d];
        }
        __syncthreads();
        int k = kt0 + lane;
#pragma unroll
        for (int rr = 0; rr < 2; ++rr) {
            int row = wave * 2 + rr;
            int q0 = qbase + row;
            if (k <= q0) {
                float s = 0.0f;
#pragma unroll
                for (int d = 0; d < 64; ++d) s += qs[row][d] * KV[lane][d];
                sc[rr][tile] = s * 0.125f;
            }
        }
    }

#pragma unroll
    for (int rr = 0; rr < 2; ++rr) {
        int row = wave * 2 + rr;
        float mx = -1e30f;
#pragma unroll
        for (int t = 0; t < 16; ++t) mx = fmaxf(mx, sc[rr][t]);
#pragma unroll
        for (int m2 = 32; m2 >= 1; m2 >>= 1) mx = fmaxf(mx, __shfl_xor(mx, m2, 64));
        float p[16];
        float psum = 0.0f;
#pragma unroll
        for (int t = 0; t < 16; ++t) {
            float pv = (sc[rr][t] > -1e29f) ? expf(sc[rr][t] - mx) : 0.0f;
            p[t] = pv;
            psum += pv;
        }
        psum = wred_sum(psum);
        float inv = 1.0f / psum;
        float msum = 0.0f;
#pragma unroll
        for (int t = 0; t < 16; ++t) {
            float pp = p[t] * inv;
            float fire = 1.0f / (1.0f + expf(-st * (pp - th)));
            float wgt = fire + lk * (1.0f - fire);
            float md = pp * wgt;
            p[t] = md;
            msum += md;
        }
        msum = wred_sum(msum);
        float inv2 = 1.0f / (msum + 1e-8f);
#pragma unroll
        for (int t = 0; t < 16; ++t) mods[row][t * 64 + lane] = p[t] * inv2;
    }

    float acc[2] = {0.0f, 0.0f};
    __syncthreads();
    for (int tile = 0; tile < ntiles; ++tile) {
        const int kt0 = tile << 6;
#pragma unroll
        for (int p2 = 0; p2 < 16; ++p2) {
            int i2 = p2 * 256 + tid;
            int r = i2 >> 6, d = i2 & 63;
            KV[r][d] = qkv[(size_t)(b * T_ + kt0 + r) * C3_ + 2 * C_ + hh * DH_ + d];
        }
        __syncthreads();
#pragma unroll
        for (int rr = 0; rr < 2; ++rr) {
            int row = wave * 2 + rr;
            int q0 = qbase + row;
            int kmax = q0 - kt0;
            if (kmax > 63) kmax = 63;
            for (int r2 = 0; r2 <= kmax; ++r2)
                acc[rr] += mods[row][kt0 + r2] * KV[r2][lane];
        }
        __syncthreads();
    }
#pragma unroll
    for (int rr = 0; rr < 2; ++rr) {
        int q0 = qbase + wave * 2 + rr;
        y[(size_t)(b * T_ + q0) * C_ + hh * DH_ + lane] = f2bf(acc[rr]);
    }
}

// ---------------- tied LM head ----------------
__global__ __launch_bounds__(256) void logits_kernel(const float* __restrict__ xf,
                                                     const float* __restrict__ wte,
                                                     float* __restrict__ out) {
    __shared__ float xs[8 * 768];
    int tid = threadIdx.x;
#pragma unroll
    for (int p = 0; p < 24; ++p) xs[p * 256 + tid] = xf[p * 256 + tid];
    __syncthreads();
    int lane = tid & 63, wave = tid >> 6;
    int v = blockIdx.x * 4 + wave;
    if (v < V_) {
        float acc[8] = {};
        for (int cc = lane; cc < 768; cc += 64) {
            float wv = wte[(size_t)v * C_ + cc];
#pragma unroll
            for (int b2 = 0; b2 < 8; ++b2) acc[b2] += wv * xs[b2 * 768 + cc];
        }
#pragma unroll
        for (int b2 = 0; b2 < 8; ++b2) {
            float r = wred_sum(acc[b2]);
            if (lane == 0) out[(size_t)b2 * V_ + v] = r;
        }
    }
}

extern "C" void kernel_launch(void* const* d_in, const int* in_sizes, int n_in,
                              void* d_out, int out_size, void* d_ws, size_t ws_size,
                              hipStream_t stream) {
    (void)in_sizes; (void)n_in; (void)out_size; (void)ws_size;
    const int*   idx     = (const int*)d_in[0];
    const float* wte     = (const float*)d_in[1];
    const float* wpe     = (const float*)d_in[2];
    const float* ln1_w   = (const float*)d_in[3];
    const float* ln1_b   = (const float*)d_in[4];
    const float* attn_w  = (const float*)d_in[5];
    const float* attn_b  = (const float*)d_in[6];
    const float* proj_w  = (const float*)d_in[7];
    const float* proj_b  = (const float*)d_in[8];
    const float* thr     = (const float*)d_in[9];
    const float* leak    = (const float*)d_in[10];
    const float* steep   = (const float*)d_in[11];
    const float* ln2_w   = (const float*)d_in[12];
    const float* ln2_b   = (const float*)d_in[13];
    const float* fc_w    = (const float*)d_in[14];
    const float* fc_b    = (const float*)d_in[15];
    const float* mproj_w = (const float*)d_in[16];
    const float* mproj_b = (const float*)d_in[17];
    const float* lnf_w   = (const float*)d_in[18];
    const float* lnf_b   = (const float*)d_in[19];
    float* out = (float*)d_out;

    char* ws = (char*)d_ws;
    float* x    = (float*)ws;                       ws += (size_t)BT_ * C_ * 4;
    float* qkv  = (float*)ws;  char* qkv_raw = ws;  ws += (size_t)BT_ * C3_ * 4;
    float* xf   = (float*)ws;                       ws += 8 * C_ * 4;
    unsigned short* h_bf   = (unsigned short*)ws;   ws += (size_t)BT_ * C_ * 2;
    unsigned short* y_bf   = (unsigned short*)ws;   ws += (size_t)BT_ * C_ * 2;
    unsigned short* wqkv   = (unsigned short*)ws;   ws += (size_t)L_ * C3_ * C_ * 2;
    unsigned short* wproj  = (unsigned short*)ws;   ws += (size_t)L_ * C_ * C_ * 2;
    unsigned short* wfc    = (unsigned short*)ws;   ws += (size_t)L_ * C4_ * C_ * 2;
    unsigned short* wmproj = (unsigned short*)ws;   ws += (size_t)L_ * C_ * C4_ * 2;
    unsigned short* m_bf   = (unsigned short*)qkv_raw;   // reuse: qkv dead after attn

    // weight conversion (each elem count divisible by 1024)
    cvt_bf16<<<(L_ * C3_ * C_) / 1024, 256, 0, stream>>>(attn_w, wqkv);
    cvt_bf16<<<(L_ * C_ * C_) / 1024, 256, 0, stream>>>(proj_w, wproj);
    cvt_bf16<<<(L_ * C4_ * C_) / 1024, 256, 0, stream>>>(fc_w, wfc);
    cvt_bf16<<<(L_ * C_ * C4_) / 1024, 256, 0, stream>>>(mproj_w, wmproj);

    embed_kernel<<<dim3(3, BT_), 256, 0, stream>>>(idx, wte, wpe, x);

    for (int l = 0; l < L_; ++l) {
        ln_kernel<1><<<BT_, 256, 0, stream>>>(x, ln1_w + l * C_, ln1_b + l * C_, h_bf, 1, 0);
        gemm_mfma<0, 0, 0><<<dim3(C3_ / 128, BT_ / 128), 256, 0, stream>>>(
            h_bf, wqkv + (size_t)l * C3_ * C_, attn_b + l * C3_, nullptr, qkv, BT_, C3_, C_);
        attn_kernel<<<dim3(T_ / 8, B_ * H_), 256, 0, stream>>>(
            qkv, thr + l * H_, leak + l * H_, steep + l * H_, y_bf);
        gemm_mfma<0, 1, 0><<<dim3(C_ / 128, BT_ / 128), 256, 0, stream>>>(
            y_bf, wproj + (size_t)l * C_ * C_, proj_b + l * C_, x, x, BT_, C_, C_);
        ln_kernel<1><<<BT_, 256, 0, stream>>>(x, ln2_w + l * C_, ln2_b + l * C_, h_bf, 1, 0);
        gemm_mfma<1, 0, 1><<<dim3(C4_ / 128, BT_ / 128), 256, 0, stream>>>(
            h_bf, wfc + (size_t)l * C4_ * C_, fc_b + l * C4_, nullptr, m_bf, BT_, C4_, C_);
        gemm_mfma<0, 1, 0><<<dim3(C_ / 128, BT_ / 128), 256, 0, stream>>>(
            m_bf, wmproj + (size_t)l * C_ * C4_, mproj_b + l * C_, x, x, BT_, C_, C4_);
    }

    ln_kernel<0><<<8, 256, 0, stream>>>(x, lnf_w, lnf_b, xf, T_, T_ - 1);
    logits_kernel<<<(V_ + 3) / 4, 256, 0, stream>>>(xf, wte, out);
}

// Round 3
// 2725.093 us; speedup vs baseline: 7.2445x; 2.7797x over previous
//
#include <hip/hip_runtime.h>
#include <hip/hip_bf16.h>
#include <math.h>

#define L_ 6
#define C_ 768
#define H_ 12
#define T_ 1024
#define B_ 8
#define V_ 50257
#define DH_ 64
#define C3_ 2304
#define C4_ 3072
#define BT_ 8192

typedef __attribute__((ext_vector_type(8))) short short8;
typedef __attribute__((ext_vector_type(4))) float f32x4;

__device__ __forceinline__ float wred_sum(float v) {
#pragma unroll
    for (int m = 32; m >= 1; m >>= 1) v += __shfl_xor(v, m, 64);
    return v;
}

__device__ __forceinline__ unsigned short f2bf(float f) {
    unsigned u = __builtin_bit_cast(unsigned, f);
    u += 0x7fffu + ((u >> 16) & 1u);   // round-to-nearest-even
    return (unsigned short)(u >> 16);
}

// ---------------- f32 -> bf16 bulk convert (weights) ----------------
__global__ __launch_bounds__(256) void cvt_bf16(const float* __restrict__ in,
                                                unsigned short* __restrict__ out) {
    size_t i = ((size_t)blockIdx.x * 256 + threadIdx.x) * 4;
    float4 v = *(const float4*)(in + i);
    ushort4 o;
    o.x = f2bf(v.x); o.y = f2bf(v.y); o.z = f2bf(v.z); o.w = f2bf(v.w);
    *(ushort4*)(out + i) = o;
}

// ---------------- embedding ----------------
__global__ __launch_bounds__(256) void embed_kernel(const int* __restrict__ idx,
                                                    const float* __restrict__ wte,
                                                    const float* __restrict__ wpe,
                                                    float* __restrict__ x) {
    int c = blockIdx.x * 256 + threadIdx.x;
    int token = blockIdx.y;
    int t = token & (T_ - 1);
    int tok = idx[token];
    x[(size_t)token * C_ + c] = wte[(size_t)tok * C_ + c] + wpe[(size_t)t * C_ + c];
}

// ---------------- layernorm ----------------
template <int OBF>
__global__ __launch_bounds__(256) void ln_kernel(const float* __restrict__ in,
                                                 const float* __restrict__ w,
                                                 const float* __restrict__ bb,
                                                 void* __restrict__ outp,
                                                 int rstride, int roff) {
    int row = blockIdx.x;
    size_t base = (size_t)(row * rstride + roff) * C_;
    int tid = threadIdx.x;
    int lane = tid & 63, wave = tid >> 6;
    float v0 = in[base + tid];
    float v1 = in[base + tid + 256];
    float v2 = in[base + tid + 512];
    __shared__ float red[4];
    float s = wred_sum(v0 + v1 + v2);
    if (lane == 0) red[wave] = s;
    __syncthreads();
    float mean = (red[0] + red[1] + red[2] + red[3]) * (1.0f / 768.0f);
    __syncthreads();
    float d0 = v0 - mean, d1 = v1 - mean, d2 = v2 - mean;
    float q = wred_sum(d0 * d0 + d1 * d1 + d2 * d2);
    if (lane == 0) red[wave] = q;
    __syncthreads();
    float var = (red[0] + red[1] + red[2] + red[3]) * (1.0f / 768.0f);
    float rstd = rsqrtf(var + 1e-5f);
    size_t ob = (size_t)row * C_;
    float o0 = d0 * rstd * w[tid] + bb[tid];
    float o1 = d1 * rstd * w[tid + 256] + bb[tid + 256];
    float o2 = d2 * rstd * w[tid + 512] + bb[tid + 512];
    if (OBF) {
        unsigned short* out = (unsigned short*)outp;
        out[ob + tid] = f2bf(o0); out[ob + tid + 256] = f2bf(o1); out[ob + tid + 512] = f2bf(o2);
    } else {
        float* out = (float*)outp;
        out[ob + tid] = o0; out[ob + tid + 256] = o1; out[ob + tid + 512] = o2;
    }
}

// ---------------- bf16 MFMA GEMM (m97 structure) ----------------
template <int GELU, int RESID, int OUT_BF16>
__global__ __launch_bounds__(256) void gemm_mfma(const unsigned short* __restrict__ A,
                                                 const unsigned short* __restrict__ W,
                                                 const float* __restrict__ bias,
                                                 const float* __restrict__ resid,
                                                 void* __restrict__ outp,
                                                 int M, int N, int K) {
    __shared__ __align__(16) short As[128 * 32];
    __shared__ __align__(16) short Bs[128 * 32];
    const int tid = threadIdx.x;
    const int lane = tid & 63, wave = tid >> 6;
    const int m0 = blockIdx.y * 128, n0 = blockIdx.x * 128;
    const int wr = wave >> 1, wc = wave & 1;
    f32x4 acc[4][4] = {};

    const int srow = lane >> 2;
    const int scolb = (lane & 3) * 16;

    for (int kt = 0; kt < K; kt += 32) {
#pragma unroll
        for (int i = 0; i < 2; ++i) {
            int chunk = wave * 2 + i;
            int row = chunk * 16 + srow;
            const char* gA = (const char*)(A + (size_t)(m0 + row) * K + kt) + scolb;
            const char* gB = (const char*)(W + (size_t)(n0 + row) * K + kt) + scolb;
            __builtin_amdgcn_global_load_lds(
                (const __attribute__((address_space(1))) void*)gA,
                (__attribute__((address_space(3))) void*)((char*)As + chunk * 1024 + lane * 16),
                16, 0, 0);
            __builtin_amdgcn_global_load_lds(
                (const __attribute__((address_space(1))) void*)gB,
                (__attribute__((address_space(3))) void*)((char*)Bs + chunk * 1024 + lane * 16),
                16, 0, 0);
        }
        __syncthreads();
        const int fr = lane & 15, kq = lane >> 4;
        short8 a[4], b[4];
#pragma unroll
        for (int m = 0; m < 4; ++m)
            a[m] = *(const short8*)(&As[(wr * 64 + m * 16 + fr) * 32 + kq * 8]);
#pragma unroll
        for (int n = 0; n < 4; ++n)
            b[n] = *(const short8*)(&Bs[(wc * 64 + n * 16 + fr) * 32 + kq * 8]);
#pragma unroll
        for (int m = 0; m < 4; ++m)
#pragma unroll
            for (int n = 0; n < 4; ++n)
                acc[m][n] = __builtin_amdgcn_mfma_f32_16x16x32_bf16(a[m], b[n], acc[m][n], 0, 0, 0);
        __syncthreads();
    }

    const int fr = lane & 15, rq = lane >> 4;
#pragma unroll
    for (int m = 0; m < 4; ++m) {
        int rbase = m0 + wr * 64 + m * 16 + rq * 4;
#pragma unroll
        for (int n = 0; n < 4; ++n) {
            int col = n0 + wc * 64 + n * 16 + fr;
            float bv = bias[col];
#pragma unroll
            for (int j = 0; j < 4; ++j) {
                int row = rbase + j;
                float c = acc[m][n][j] + bv;
                if (GELU) c = 0.5f * c * (1.0f + erff(c * 0.70710678118654752f));
                if (RESID) c += resid[(size_t)row * N + col];
                if (OUT_BF16)
                    ((unsigned short*)outp)[(size_t)row * N + col] = f2bf(c);
                else
                    ((float*)outp)[(size_t)row * N + col] = c;
            }
        }
    }
}

// ---------------- MFMA attention with LIF gating, two-pass flash ----------------
// grid (16, 96): qt = 15-bx, bh = by. 256 threads = 4 waves, 64 q-rows/block (16/wave).
// Pass A: online (m,l) over causal K tiles. Pass B: recompute S, gate, PV.
__global__ __launch_bounds__(256) void attn_mfma(const unsigned short* __restrict__ qkv,
                                                 const float* __restrict__ thr,
                                                 const float* __restrict__ leak,
                                                 const float* __restrict__ steep,
                                                 unsigned short* __restrict__ y) {
    __shared__ __align__(16) short Ks[64 * 64];   // K tile, XOR-swizzled chunks, linear rows of 128B
    __shared__ __align__(16) short Vt[64 * 72];   // V^T [d][t], +8 pad
    __shared__ __align__(16) short Ps[64 * 72];   // mod bf16 [q][t], +8 pad (wave-private rows)
    const int tid = threadIdx.x;
    const int lane = tid & 63, wave = tid >> 6;
    const int bh = blockIdx.y;
    const int b = bh / H_, h = bh % H_;
    const int qt = (int)(gridDim.x - 1) - blockIdx.x;   // long blocks first
    const int q0 = qt * 64;

    const float th = fabsf(thr[h]) * 0.1f;
    const float lk = 1.0f / (1.0f + expf(-leak[h]));
    const float stv = steep[h];
    const float st = (stv > 15.0f) ? stv : log1pf(expf(stv));

    const int arow = lane & 15;         // A-frag row / B-frag col / D col
    const int kq = lane >> 4;           // k-quad
    const int drow0 = kq * 4;           // D rows drow0..drow0+3

    // Q fragments (held in registers for both passes)
    const unsigned short* qptr = qkv + (size_t)((size_t)(b * T_ + q0 + wave * 16 + arow)) * C3_ + h * DH_ + kq * 8;
    short8 qf[2];
    qf[0] = *(const short8*)qptr;
    qf[1] = *(const short8*)(qptr + 32);

    // K staging geometry (same both passes)
    const int ksrow = wave * 16 + (lane >> 3);   // +8 for i=1
    const int ksc = lane & 7;

    float mrun[4], lrun[4];
#pragma unroll
    for (int j = 0; j < 4; ++j) { mrun[j] = -1e30f; lrun[j] = 0.0f; }

    // ================= PASS A: row max + denominator =================
    for (int kt = 0; kt <= qt; ++kt) {
        const int kt0 = kt * 64;
        __syncthreads();
#pragma unroll
        for (int i = 0; i < 2; ++i) {
            int row = ksrow + i * 8;
            int kqe = ksc ^ (row & 7);
            const unsigned short* src = qkv + (size_t)(b * T_ + kt0 + row) * C3_ + C_ + h * DH_ + kqe * 8;
            __builtin_amdgcn_global_load_lds(
                (const __attribute__((address_space(1))) void*)src,
                (__attribute__((address_space(3))) void*)((char*)Ks + wave * 2048 + i * 1024 + lane * 16),
                16, 0, 0);
        }
        __syncthreads();
        f32x4 sf[4] = {};
#pragma unroll
        for (int kc = 0; kc < 2; ++kc) {
#pragma unroll
            for (int n = 0; n < 4; ++n) {
                int row = n * 16 + arow;
                int chunk = (kc * 4 + kq) ^ (row & 7);
                short8 kf = *(const short8*)((char*)Ks + row * 128 + chunk * 16);
                sf[n] = __builtin_amdgcn_mfma_f32_16x16x32_bf16(qf[kc], kf, sf[n], 0, 0, 0);
            }
        }
        float s[4][4];
        const bool diag = (kt == qt);
#pragma unroll
        for (int n = 0; n < 4; ++n) {
            int col = kt0 + n * 16 + arow;
#pragma unroll
            for (int j = 0; j < 4; ++j) {
                float v = sf[n][j] * 0.125f;
                if (diag && col > q0 + wave * 16 + drow0 + j) v = -1e30f;
                s[n][j] = v;
            }
        }
#pragma unroll
        for (int j = 0; j < 4; ++j) {
            float tmax = fmaxf(fmaxf(s[0][j], s[1][j]), fmaxf(s[2][j], s[3][j]));
#pragma unroll
            for (int m2 = 8; m2 >= 1; m2 >>= 1) tmax = fmaxf(tmax, __shfl_xor(tmax, m2, 64));
            float mnew = fmaxf(mrun[j], tmax);
            float corr = __expf(mrun[j] - mnew);
            float ls = 0.0f;
#pragma unroll
            for (int n = 0; n < 4; ++n) ls += __expf(s[n][j] - mnew);
            lrun[j] = lrun[j] * corr + ls;
            mrun[j] = mnew;
        }
    }
    float rinv[4];
#pragma unroll
    for (int j = 0; j < 4; ++j) {
        float lt = lrun[j];
#pragma unroll
        for (int m2 = 8; m2 >= 1; m2 >>= 1) lt += __shfl_xor(lt, m2, 64);
        rinv[j] = 1.0f / lt;
    }

    // ================= PASS B: gate + PV =================
    f32x4 accy[4] = {};
    float msum[4] = {0.0f, 0.0f, 0.0f, 0.0f};

    for (int kt = 0; kt <= qt; ++kt) {
        const int kt0 = kt * 64;
        __syncthreads();
        // stage K (swizzled, async)
#pragma unroll
        for (int i = 0; i < 2; ++i) {
            int row = ksrow + i * 8;
            int kqe = ksc ^ (row & 7);
            const unsigned short* src = qkv + (size_t)(b * T_ + kt0 + row) * C3_ + C_ + h * DH_ + kqe * 8;
            __builtin_amdgcn_global_load_lds(
                (const __attribute__((address_space(1))) void*)src,
                (__attribute__((address_space(3))) void*)((char*)Ks + wave * 2048 + i * 1024 + lane * 16),
                16, 0, 0);
        }
        // stage V transposed: Vt[d][t] = V[t][d]
#pragma unroll
        for (int cc = 0; cc < 2; ++cc) {
            int c = tid + cc * 256;
            int t = c & 63, d0 = (c >> 6) * 8;
            short8 vv = *(const short8*)(qkv + (size_t)(b * T_ + kt0 + t) * C3_ + 2 * C_ + h * DH_ + d0);
#pragma unroll
            for (int e = 0; e < 8; ++e) Vt[(d0 + e) * 72 + t] = vv[e];
        }
        __syncthreads();
        // recompute S
        f32x4 sf[4] = {};
#pragma unroll
        for (int kc = 0; kc < 2; ++kc) {
#pragma unroll
            for (int n = 0; n < 4; ++n) {
                int row = n * 16 + arow;
                int chunk = (kc * 4 + kq) ^ (row & 7);
                short8 kf = *(const short8*)((char*)Ks + row * 128 + chunk * 16);
                sf[n] = __builtin_amdgcn_mfma_f32_16x16x32_bf16(qf[kc], kf, sf[n], 0, 0, 0);
            }
        }
        const bool diag = (kt == qt);
#pragma unroll
        for (int n = 0; n < 4; ++n) {
            int col = kt0 + n * 16 + arow;
#pragma unroll
            for (int j = 0; j < 4; ++j) {
                float v = sf[n][j] * 0.125f;
                if (diag && col > q0 + wave * 16 + drow0 + j) v = -1e30f;
                float p = __expf(v - mrun[j]) * rinv[j];
                float e = __expf(-st * (p - th));
                float fire = __builtin_amdgcn_rcpf(1.0f + e);
                float wgt = fire + lk * (1.0f - fire);
                float mod = p * wgt;
                msum[j] += mod;
                Ps[(wave * 16 + drow0 + j) * 72 + n * 16 + arow] = (short)f2bf(mod);
            }
        }
        // PV: wave-private P rows; compiler orders ds_write->ds_read via lgkmcnt
#pragma unroll
        for (int kc = 0; kc < 2; ++kc) {
            short8 pa = *(const short8*)((char*)Ps + (wave * 16 + arow) * 144 + (kc * 4 + kq) * 16);
#pragma unroll
            for (int nd = 0; nd < 4; ++nd) {
                short8 vf = *(const short8*)((char*)Vt + (nd * 16 + arow) * 144 + (kc * 4 + kq) * 16);
                accy[nd] = __builtin_amdgcn_mfma_f32_16x16x32_bf16(pa, vf, accy[nd], 0, 0, 0);
            }
        }
    }

    // epilogue: divide by mod-sum, write y
#pragma unroll
    for (int j = 0; j < 4; ++j) {
        float mt = msum[j];
#pragma unroll
        for (int m2 = 8; m2 >= 1; m2 >>= 1) mt += __shfl_xor(mt, m2, 64);
        msum[j] = 1.0f / (mt + 1e-8f);
    }
#pragma unroll
    for (int nd = 0; nd < 4; ++nd) {
#pragma unroll
        for (int j = 0; j < 4; ++j) {
            int row = q0 + wave * 16 + drow0 + j;
            int col = h * DH_ + nd * 16 + arow;
            y[(size_t)(b * T_ + row) * C_ + col] = f2bf(accy[nd][j] * msum[j]);
        }
    }
}

// ---------------- tied LM head ----------------
__global__ __launch_bounds__(256) void logits_kernel(const float* __restrict__ xf,
                                                     const float* __restrict__ wte,
                                                     float* __restrict__ out) {
    __shared__ float xs[8 * 768];
    int tid = threadIdx.x;
#pragma unroll
    for (int p = 0; p < 24; ++p) xs[p * 256 + tid] = xf[p * 256 + tid];
    __syncthreads();
    int lane = tid & 63, wave = tid >> 6;
    int v = blockIdx.x * 4 + wave;
    if (v < V_) {
        float acc[8] = {};
        for (int cc = lane; cc < 768; cc += 64) {
            float wv = wte[(size_t)v * C_ + cc];
#pragma unroll
            for (int b2 = 0; b2 < 8; ++b2) acc[b2] += wv * xs[b2 * 768 + cc];
        }
#pragma unroll
        for (int b2 = 0; b2 < 8; ++b2) {
            float r = wred_sum(acc[b2]);
            if (lane == 0) out[(size_t)b2 * V_ + v] = r;
        }
    }
}

extern "C" void kernel_launch(void* const* d_in, const int* in_sizes, int n_in,
                              void* d_out, int out_size, void* d_ws, size_t ws_size,
                              hipStream_t stream) {
    (void)in_sizes; (void)n_in; (void)out_size; (void)ws_size;
    const int*   idx     = (const int*)d_in[0];
    const float* wte     = (const float*)d_in[1];
    const float* wpe     = (const float*)d_in[2];
    const float* ln1_w   = (const float*)d_in[3];
    const float* ln1_b   = (const float*)d_in[4];
    const float* attn_w  = (const float*)d_in[5];
    const float* attn_b  = (const float*)d_in[6];
    const float* proj_w  = (const float*)d_in[7];
    const float* proj_b  = (const float*)d_in[8];
    const float* thr     = (const float*)d_in[9];
    const float* leak    = (const float*)d_in[10];
    const float* steep   = (const float*)d_in[11];
    const float* ln2_w   = (const float*)d_in[12];
    const float* ln2_b   = (const float*)d_in[13];
    const float* fc_w    = (const float*)d_in[14];
    const float* fc_b    = (const float*)d_in[15];
    const float* mproj_w = (const float*)d_in[16];
    const float* mproj_b = (const float*)d_in[17];
    const float* lnf_w   = (const float*)d_in[18];
    const float* lnf_b   = (const float*)d_in[19];
    float* out = (float*)d_out;

    char* ws = (char*)d_ws;
    float* x    = (float*)ws;                       ws += (size_t)BT_ * C_ * 4;
    float* xf   = (float*)ws;                       ws += 8 * C_ * 4 + 1024;
    unsigned short* qkv_bf = (unsigned short*)ws;   ws += (size_t)BT_ * C3_ * 2;
    unsigned short* h_bf   = (unsigned short*)ws;   ws += (size_t)BT_ * C_ * 2;
    unsigned short* y_bf   = (unsigned short*)ws;   ws += (size_t)BT_ * C_ * 2;
    unsigned short* m_bf   = (unsigned short*)ws;   ws += (size_t)BT_ * C4_ * 2;
    unsigned short* wqkv   = (unsigned short*)ws;   ws += (size_t)L_ * C3_ * C_ * 2;
    unsigned short* wproj  = (unsigned short*)ws;   ws += (size_t)L_ * C_ * C_ * 2;
    unsigned short* wfc    = (unsigned short*)ws;   ws += (size_t)L_ * C4_ * C_ * 2;
    unsigned short* wmproj = (unsigned short*)ws;   ws += (size_t)L_ * C_ * C4_ * 2;

    cvt_bf16<<<(L_ * C3_ * C_) / 1024, 256, 0, stream>>>(attn_w, wqkv);
    cvt_bf16<<<(L_ * C_ * C_) / 1024, 256, 0, stream>>>(proj_w, wproj);
    cvt_bf16<<<(L_ * C4_ * C_) / 1024, 256, 0, stream>>>(fc_w, wfc);
    cvt_bf16<<<(L_ * C_ * C4_) / 1024, 256, 0, stream>>>(mproj_w, wmproj);

    embed_kernel<<<dim3(3, BT_), 256, 0, stream>>>(idx, wte, wpe, x);

    for (int l = 0; l < L_; ++l) {
        ln_kernel<1><<<BT_, 256, 0, stream>>>(x, ln1_w + l * C_, ln1_b + l * C_, h_bf, 1, 0);
        gemm_mfma<0, 0, 1><<<dim3(C3_ / 128, BT_ / 128), 256, 0, stream>>>(
            h_bf, wqkv + (size_t)l * C3_ * C_, attn_b + l * C3_, nullptr, qkv_bf, BT_, C3_, C_);
        attn_mfma<<<dim3(T_ / 64, B_ * H_), 256, 0, stream>>>(
            qkv_bf, thr + l * H_, leak + l * H_, steep + l * H_, y_bf);
        gemm_mfma<0, 1, 0><<<dim3(C_ / 128, BT_ / 128), 256, 0, stream>>>(
            y_bf, wproj + (size_t)l * C_ * C_, proj_b + l * C_, x, x, BT_, C_, C_);
        ln_kernel<1><<<BT_, 256, 0, stream>>>(x, ln2_w + l * C_, ln2_b + l * C_, h_bf, 1, 0);
        gemm_mfma<1, 0, 1><<<dim3(C4_ / 128, BT_ / 128), 256, 0, stream>>>(
            h_bf, wfc + (size_t)l * C4_ * C_, fc_b + l * C4_, nullptr, m_bf, BT_, C4_, C_);
        gemm_mfma<0, 1, 0><<<dim3(C_ / 128, BT_ / 128), 256, 0, stream>>>(
            m_bf, wmproj + (size_t)l * C_ * C4_, mproj_b + l * C_, x, x, BT_, C_, C4_);
    }

    ln_kernel<0><<<8, 256, 0, stream>>>(x, lnf_w, lnf_b, xf, T_, T_ - 1);
    logits_kernel<<<(V_ + 3) / 4, 256, 0, stream>>>(xf, wte, out);
}

// Round 4
// 2156.836 us; speedup vs baseline: 9.1532x; 1.2635x over previous
//
#include <hip/hip_runtime.h>
#include <hip/hip_bf16.h>
#include <math.h>

#define L_ 6
#define C_ 768
#define H_ 12
#define T_ 1024
#define B_ 8
#define V_ 50257
#define DH_ 64
#define C3_ 2304
#define C4_ 3072
#define BT_ 8192

typedef __attribute__((ext_vector_type(8))) short short8;
typedef __attribute__((ext_vector_type(4))) float f32x4;

__device__ __forceinline__ float wred_sum(float v) {
#pragma unroll
    for (int m = 32; m >= 1; m >>= 1) v += __shfl_xor(v, m, 64);
    return v;
}

__device__ __forceinline__ unsigned short f2bf(float f) {
    unsigned u = __builtin_bit_cast(unsigned, f);
    u += 0x7fffu + ((u >> 16) & 1u);   // round-to-nearest-even
    return (unsigned short)(u >> 16);
}

// ---------------- f32 -> bf16 bulk convert (weights) ----------------
__global__ __launch_bounds__(256) void cvt_bf16(const float* __restrict__ in,
                                                unsigned short* __restrict__ out) {
    size_t i = ((size_t)blockIdx.x * 256 + threadIdx.x) * 4;
    float4 v = *(const float4*)(in + i);
    ushort4 o;
    o.x = f2bf(v.x); o.y = f2bf(v.y); o.z = f2bf(v.z); o.w = f2bf(v.w);
    *(ushort4*)(out + i) = o;
}

// ---------------- embedding ----------------
__global__ __launch_bounds__(256) void embed_kernel(const int* __restrict__ idx,
                                                    const float* __restrict__ wte,
                                                    const float* __restrict__ wpe,
                                                    float* __restrict__ x) {
    int c = blockIdx.x * 256 + threadIdx.x;
    int token = blockIdx.y;
    int t = token & (T_ - 1);
    int tok = idx[token];
    x[(size_t)token * C_ + c] = wte[(size_t)tok * C_ + c] + wpe[(size_t)t * C_ + c];
}

// ---------------- layernorm ----------------
template <int OBF>
__global__ __launch_bounds__(256) void ln_kernel(const float* __restrict__ in,
                                                 const float* __restrict__ w,
                                                 const float* __restrict__ bb,
                                                 void* __restrict__ outp,
                                                 int rstride, int roff) {
    int row = blockIdx.x;
    size_t base = (size_t)(row * rstride + roff) * C_;
    int tid = threadIdx.x;
    int lane = tid & 63, wave = tid >> 6;
    float v0 = in[base + tid];
    float v1 = in[base + tid + 256];
    float v2 = in[base + tid + 512];
    __shared__ float red[4];
    float s = wred_sum(v0 + v1 + v2);
    if (lane == 0) red[wave] = s;
    __syncthreads();
    float mean = (red[0] + red[1] + red[2] + red[3]) * (1.0f / 768.0f);
    __syncthreads();
    float d0 = v0 - mean, d1 = v1 - mean, d2 = v2 - mean;
    float q = wred_sum(d0 * d0 + d1 * d1 + d2 * d2);
    if (lane == 0) red[wave] = q;
    __syncthreads();
    float var = (red[0] + red[1] + red[2] + red[3]) * (1.0f / 768.0f);
    float rstd = rsqrtf(var + 1e-5f);
    size_t ob = (size_t)row * C_;
    float o0 = d0 * rstd * w[tid] + bb[tid];
    float o1 = d1 * rstd * w[tid + 256] + bb[tid + 256];
    float o2 = d2 * rstd * w[tid + 512] + bb[tid + 512];
    if (OBF) {
        unsigned short* out = (unsigned short*)outp;
        out[ob + tid] = f2bf(o0); out[ob + tid + 256] = f2bf(o1); out[ob + tid + 512] = f2bf(o2);
    } else {
        float* out = (float*)outp;
        out[ob + tid] = o0; out[ob + tid + 256] = o1; out[ob + tid + 512] = o2;
    }
}

// ---------------- bf16 MFMA GEMM, double-buffered single-barrier pipeline ----------------
// 128x128 tile, BK=32, 4 waves (2x2). XCD-swizzled flat block id (grid count % 8 == 0).
template <int GELU, int RESID, int OUT_BF16>
__global__ __launch_bounds__(256) void gemm_mfma(const unsigned short* __restrict__ A,
                                                 const unsigned short* __restrict__ W,
                                                 const float* __restrict__ bias,
                                                 const float* __restrict__ resid,
                                                 void* __restrict__ outp,
                                                 int M, int N, int K) {
    __shared__ __align__(16) short As[2][128 * 32];
    __shared__ __align__(16) short Bs[2][128 * 32];
    const int tid = threadIdx.x;
    const int lane = tid & 63, wave = tid >> 6;

    // XCD swizzle: contiguous tiles per XCD (same A panel -> L2 reuse)
    const int nbx = gridDim.x;
    const int ntile = nbx * gridDim.y;
    const int fblk = blockIdx.x + nbx * blockIdx.y;
    const int tile = (fblk & 7) * (ntile >> 3) + (fblk >> 3);
    const int m0 = (tile / nbx) * 128, n0 = (tile % nbx) * 128;

    const int wr = wave >> 1, wc = wave & 1;
    f32x4 acc[4][4] = {};

    const int srow = lane >> 2;
    const int scolb = (lane & 3) * 16;

#define STAGE_G(bufA, bufB, ktel)                                                        \
    do {                                                                                 \
        _Pragma("unroll") for (int i_ = 0; i_ < 2; ++i_) {                               \
            int chunk_ = wave * 2 + i_;                                                  \
            int row_ = chunk_ * 16 + srow;                                               \
            const char* gA_ = (const char*)(A + (size_t)(m0 + row_) * K + (ktel)) + scolb; \
            const char* gB_ = (const char*)(W + (size_t)(n0 + row_) * K + (ktel)) + scolb; \
            __builtin_amdgcn_global_load_lds(                                            \
                (const __attribute__((address_space(1))) void*)gA_,                      \
                (__attribute__((address_space(3))) void*)((bufA) + chunk_ * 1024 + lane * 16), \
                16, 0, 0);                                                               \
            __builtin_amdgcn_global_load_lds(                                            \
                (const __attribute__((address_space(1))) void*)gB_,                      \
                (__attribute__((address_space(3))) void*)((bufB) + chunk_ * 1024 + lane * 16), \
                16, 0, 0);                                                               \
        }                                                                                \
    } while (0)

    char* A0 = (char*)As;       char* A1 = (char*)As + 8192;
    char* B0 = (char*)Bs;       char* B1 = (char*)Bs + 8192;

    STAGE_G(A0, B0, 0);
    __syncthreads();            // drains vmcnt(0): buf0 ready

    const int nk = K >> 5;
    const int fr = lane & 15, kq = lane >> 4;
    for (int t = 0; t < nk; ++t) {
        char* curA = (t & 1) ? A1 : A0;
        char* curB = (t & 1) ? B1 : B0;
        char* nxtA = (t & 1) ? A0 : A1;
        char* nxtB = (t & 1) ? B0 : B1;
        if (t + 1 < nk) STAGE_G(nxtA, nxtB, (t + 1) * 32);   // overlaps with compute below
        short8 a[4], b[4];
#pragma unroll
        for (int m = 0; m < 4; ++m)
            a[m] = *(const short8*)(curA + (wr * 64 + m * 16 + fr) * 64 + kq * 16);
#pragma unroll
        for (int n = 0; n < 4; ++n)
            b[n] = *(const short8*)(curB + (wc * 64 + n * 16 + fr) * 64 + kq * 16);
#pragma unroll
        for (int m = 0; m < 4; ++m)
#pragma unroll
            for (int n = 0; n < 4; ++n)
                acc[m][n] = __builtin_amdgcn_mfma_f32_16x16x32_bf16(a[m], b[n], acc[m][n], 0, 0, 0);
        __syncthreads();        // one barrier per K-step: drains stage, guards buf reuse
    }
#undef STAGE_G

    const int rq = lane >> 4;
#pragma unroll
    for (int m = 0; m < 4; ++m) {
        int rbase = m0 + wr * 64 + m * 16 + rq * 4;
#pragma unroll
        for (int n = 0; n < 4; ++n) {
            int col = n0 + wc * 64 + n * 16 + fr;
            float bv = bias[col];
#pragma unroll
            for (int j = 0; j < 4; ++j) {
                int row = rbase + j;
                float c = acc[m][n][j] + bv;
                if (GELU) c = 0.5f * c * (1.0f + erff(c * 0.70710678118654752f));
                if (RESID) c += resid[(size_t)row * N + col];
                if (OUT_BF16)
                    ((unsigned short*)outp)[(size_t)row * N + col] = f2bf(c);
                else
                    ((float*)outp)[(size_t)row * N + col] = c;
            }
        }
    }
}

// ---------------- MFMA attention with LIF gating, two-pass flash ----------------
// grid (768): f -> xcd = f&7 owns 12 heads; each block does q-tile pair (15-slot, slot).
__global__ __launch_bounds__(256) void attn_mfma(const unsigned short* __restrict__ qkv,
                                                 const float* __restrict__ thr,
                                                 const float* __restrict__ leak,
                                                 const float* __restrict__ steep,
                                                 unsigned short* __restrict__ y) {
    __shared__ __align__(16) short Ks[64 * 64];   // K tile, XOR-swizzled chunks
    __shared__ __align__(16) short Vt[64 * 72];   // V^T [d][t], +8 pad
    __shared__ __align__(16) short Ps[64 * 72];   // mod bf16 [q][t], +8 pad
    const int tid = threadIdx.x;
    const int lane = tid & 63, wave = tid >> 6;
    const int f = blockIdx.x;
    const int xcd = f & 7, idxq = f >> 3;         // idxq in [0,96)
    const int bh = xcd * 12 + (idxq >> 3);        // 12 heads per XCD -> K/V fits L2
    const int slot = idxq & 7;
    const int b = bh / H_, h = bh % H_;

    const float th = fabsf(thr[h]) * 0.1f;
    const float lk = 1.0f / (1.0f + expf(-leak[h]));
    const float stv = steep[h];
    const float st = (stv > 15.0f) ? stv : log1pf(expf(stv));

    const int arow = lane & 15;
    const int kq = lane >> 4;
    const int drow0 = kq * 4;
    const int ksrow = wave * 16 + (lane >> 3);
    const int ksc = lane & 7;

    for (int pi = 0; pi < 2; ++pi) {
        const int qt = pi ? slot : 15 - slot;     // pair: work = 17 tiles, all blocks equal
        const int q0 = qt * 64;

        const unsigned short* qptr = qkv + (size_t)(b * T_ + q0 + wave * 16 + arow) * C3_ + h * DH_ + kq * 8;
        short8 qf[2];
        qf[0] = *(const short8*)qptr;
        qf[1] = *(const short8*)(qptr + 32);

        float mrun[4], lrun[4];
#pragma unroll
        for (int j = 0; j < 4; ++j) { mrun[j] = -1e30f; lrun[j] = 0.0f; }

        // ================= PASS A: row max + denominator =================
        for (int kt = 0; kt <= qt; ++kt) {
            const int kt0 = kt * 64;
            __syncthreads();
#pragma unroll
            for (int i = 0; i < 2; ++i) {
                int row = ksrow + i * 8;
                int kqe = ksc ^ (row & 7);
                const unsigned short* src = qkv + (size_t)(b * T_ + kt0 + row) * C3_ + C_ + h * DH_ + kqe * 8;
                __builtin_amdgcn_global_load_lds(
                    (const __attribute__((address_space(1))) void*)src,
                    (__attribute__((address_space(3))) void*)((char*)Ks + wave * 2048 + i * 1024 + lane * 16),
                    16, 0, 0);
            }
            __syncthreads();
            f32x4 sf[4] = {};
            __builtin_amdgcn_s_setprio(1);
#pragma unroll
            for (int kc = 0; kc < 2; ++kc) {
#pragma unroll
                for (int n = 0; n < 4; ++n) {
                    int row = n * 16 + arow;
                    int chunk = (kc * 4 + kq) ^ (row & 7);
                    short8 kf = *(const short8*)((char*)Ks + row * 128 + chunk * 16);
                    sf[n] = __builtin_amdgcn_mfma_f32_16x16x32_bf16(qf[kc], kf, sf[n], 0, 0, 0);
                }
            }
            __builtin_amdgcn_s_setprio(0);
            float s[4][4];
            const bool diag = (kt == qt);
#pragma unroll
            for (int n = 0; n < 4; ++n) {
                int col = kt0 + n * 16 + arow;
#pragma unroll
                for (int j = 0; j < 4; ++j) {
                    float v = sf[n][j] * 0.125f;
                    if (diag && col > q0 + wave * 16 + drow0 + j) v = -1e30f;
                    s[n][j] = v;
                }
            }
#pragma unroll
            for (int j = 0; j < 4; ++j) {
                float tmax = fmaxf(fmaxf(s[0][j], s[1][j]), fmaxf(s[2][j], s[3][j]));
#pragma unroll
                for (int m2 = 8; m2 >= 1; m2 >>= 1) tmax = fmaxf(tmax, __shfl_xor(tmax, m2, 64));
                float mnew = fmaxf(mrun[j], tmax);
                float corr = __expf(mrun[j] - mnew);
                float ls = 0.0f;
#pragma unroll
                for (int n = 0; n < 4; ++n) ls += __expf(s[n][j] - mnew);
                lrun[j] = lrun[j] * corr + ls;
                mrun[j] = mnew;
            }
        }
        float rinv[4];
#pragma unroll
        for (int j = 0; j < 4; ++j) {
            float lt = lrun[j];
#pragma unroll
            for (int m2 = 8; m2 >= 1; m2 >>= 1) lt += __shfl_xor(lt, m2, 64);
            rinv[j] = 1.0f / lt;
        }

        // ================= PASS B: gate + PV =================
        f32x4 accy[4] = {};
        float msum[4] = {0.0f, 0.0f, 0.0f, 0.0f};

        for (int kt = 0; kt <= qt; ++kt) {
            const int kt0 = kt * 64;
            __syncthreads();
#pragma unroll
            for (int i = 0; i < 2; ++i) {
                int row = ksrow + i * 8;
                int kqe = ksc ^ (row & 7);
                const unsigned short* src = qkv + (size_t)(b * T_ + kt0 + row) * C3_ + C_ + h * DH_ + kqe * 8;
                __builtin_amdgcn_global_load_lds(
                    (const __attribute__((address_space(1))) void*)src,
                    (__attribute__((address_space(3))) void*)((char*)Ks + wave * 2048 + i * 1024 + lane * 16),
                    16, 0, 0);
            }
#pragma unroll
            for (int cc = 0; cc < 2; ++cc) {
                int c = tid + cc * 256;
                int t = c & 63, d0 = (c >> 6) * 8;
                short8 vv = *(const short8*)(qkv + (size_t)(b * T_ + kt0 + t) * C3_ + 2 * C_ + h * DH_ + d0);
#pragma unroll
                for (int e = 0; e < 8; ++e) Vt[(d0 + e) * 72 + t] = vv[e];
            }
            __syncthreads();
            f32x4 sf[4] = {};
            __builtin_amdgcn_s_setprio(1);
#pragma unroll
            for (int kc = 0; kc < 2; ++kc) {
#pragma unroll
                for (int n = 0; n < 4; ++n) {
                    int row = n * 16 + arow;
                    int chunk = (kc * 4 + kq) ^ (row & 7);
                    short8 kf = *(const short8*)((char*)Ks + row * 128 + chunk * 16);
                    sf[n] = __builtin_amdgcn_mfma_f32_16x16x32_bf16(qf[kc], kf, sf[n], 0, 0, 0);
                }
            }
            __builtin_amdgcn_s_setprio(0);
            const bool diag = (kt == qt);
#pragma unroll
            for (int n = 0; n < 4; ++n) {
                int col = kt0 + n * 16 + arow;
#pragma unroll
                for (int j = 0; j < 4; ++j) {
                    float v = sf[n][j] * 0.125f;
                    if (diag && col > q0 + wave * 16 + drow0 + j) v = -1e30f;
                    float p = __expf(v - mrun[j]) * rinv[j];
                    float e = __expf(-st * (p - th));
                    float fire = __builtin_amdgcn_rcpf(1.0f + e);
                    float wgt = fire + lk * (1.0f - fire);
                    float mod = p * wgt;
                    msum[j] += mod;
                    Ps[(wave * 16 + drow0 + j) * 72 + n * 16 + arow] = (short)f2bf(mod);
                }
            }
            __builtin_amdgcn_s_setprio(1);
#pragma unroll
            for (int kc = 0; kc < 2; ++kc) {
                short8 pa = *(const short8*)((char*)Ps + (wave * 16 + arow) * 144 + (kc * 4 + kq) * 16);
#pragma unroll
                for (int nd = 0; nd < 4; ++nd) {
                    short8 vf = *(const short8*)((char*)Vt + (nd * 16 + arow) * 144 + (kc * 4 + kq) * 16);
                    accy[nd] = __builtin_amdgcn_mfma_f32_16x16x32_bf16(pa, vf, accy[nd], 0, 0, 0);
                }
            }
            __builtin_amdgcn_s_setprio(0);
        }

        // epilogue
#pragma unroll
        for (int j = 0; j < 4; ++j) {
            float mt = msum[j];
#pragma unroll
            for (int m2 = 8; m2 >= 1; m2 >>= 1) mt += __shfl_xor(mt, m2, 64);
            msum[j] = 1.0f / (mt + 1e-8f);
        }
#pragma unroll
        for (int nd = 0; nd < 4; ++nd) {
#pragma unroll
            for (int j = 0; j < 4; ++j) {
                int row = q0 + wave * 16 + drow0 + j;
                int col = h * DH_ + nd * 16 + arow;
                y[(size_t)(b * T_ + row) * C_ + col] = f2bf(accy[nd][j] * msum[j]);
            }
        }
    }
}

// ---------------- tied LM head ----------------
__global__ __launch_bounds__(256) void logits_kernel(const float* __restrict__ xf,
                                                     const float* __restrict__ wte,
                                                     float* __restrict__ out) {
    __shared__ float xs[8 * 768];
    int tid = threadIdx.x;
#pragma unroll
    for (int p = 0; p < 24; ++p) xs[p * 256 + tid] = xf[p * 256 + tid];
    __syncthreads();
    int lane = tid & 63, wave = tid >> 6;
    int v = blockIdx.x * 4 + wave;
    if (v < V_) {
        float acc[8] = {};
        for (int cc = lane; cc < 768; cc += 64) {
            float wv = wte[(size_t)v * C_ + cc];
#pragma unroll
            for (int b2 = 0; b2 < 8; ++b2) acc[b2] += wv * xs[b2 * 768 + cc];
        }
#pragma unroll
        for (int b2 = 0; b2 < 8; ++b2) {
            float r = wred_sum(acc[b2]);
            if (lane == 0) out[(size_t)b2 * V_ + v] = r;
        }
    }
}

extern "C" void kernel_launch(void* const* d_in, const int* in_sizes, int n_in,
                              void* d_out, int out_size, void* d_ws, size_t ws_size,
                              hipStream_t stream) {
    (void)in_sizes; (void)n_in; (void)out_size; (void)ws_size;
    const int*   idx     = (const int*)d_in[0];
    const float* wte     = (const float*)d_in[1];
    const float* wpe     = (const float*)d_in[2];
    const float* ln1_w   = (const float*)d_in[3];
    const float* ln1_b   = (const float*)d_in[4];
    const float* attn_w  = (const float*)d_in[5];
    const float* attn_b  = (const float*)d_in[6];
    const float* proj_w  = (const float*)d_in[7];
    const float* proj_b  = (const float*)d_in[8];
    const float* thr     = (const float*)d_in[9];
    const float* leak    = (const float*)d_in[10];
    const float* steep   = (const float*)d_in[11];
    const float* ln2_w   = (const float*)d_in[12];
    const float* ln2_b   = (const float*)d_in[13];
    const float* fc_w    = (const float*)d_in[14];
    const float* fc_b    = (const float*)d_in[15];
    const float* mproj_w = (const float*)d_in[16];
    const float* mproj_b = (const float*)d_in[17];
    const float* lnf_w   = (const float*)d_in[18];
    const float* lnf_b   = (const float*)d_in[19];
    float* out = (float*)d_out;

    char* ws = (char*)d_ws;
    float* x    = (float*)ws;                       ws += (size_t)BT_ * C_ * 4;
    float* xf   = (float*)ws;                       ws += 8 * C_ * 4 + 1024;
    unsigned short* qkv_bf = (unsigned short*)ws;   ws += (size_t)BT_ * C3_ * 2;
    unsigned short* h_bf   = (unsigned short*)ws;   ws += (size_t)BT_ * C_ * 2;
    unsigned short* y_bf   = (unsigned short*)ws;   ws += (size_t)BT_ * C_ * 2;
    unsigned short* m_bf   = (unsigned short*)ws;   ws += (size_t)BT_ * C4_ * 2;
    unsigned short* wqkv   = (unsigned short*)ws;   ws += (size_t)L_ * C3_ * C_ * 2;
    unsigned short* wproj  = (unsigned short*)ws;   ws += (size_t)L_ * C_ * C_ * 2;
    unsigned short* wfc    = (unsigned short*)ws;   ws += (size_t)L_ * C4_ * C_ * 2;
    unsigned short* wmproj = (unsigned short*)ws;   ws += (size_t)L_ * C_ * C4_ * 2;

    cvt_bf16<<<(L_ * C3_ * C_) / 1024, 256, 0, stream>>>(attn_w, wqkv);
    cvt_bf16<<<(L_ * C_ * C_) / 1024, 256, 0, stream>>>(proj_w, wproj);
    cvt_bf16<<<(L_ * C4_ * C_) / 1024, 256, 0, stream>>>(fc_w, wfc);
    cvt_bf16<<<(L_ * C_ * C4_) / 1024, 256, 0, stream>>>(mproj_w, wmproj);

    embed_kernel<<<dim3(3, BT_), 256, 0, stream>>>(idx, wte, wpe, x);

    for (int l = 0; l < L_; ++l) {
        ln_kernel<1><<<BT_, 256, 0, stream>>>(x, ln1_w + l * C_, ln1_b + l * C_, h_bf, 1, 0);
        gemm_mfma<0, 0, 1><<<dim3(C3_ / 128, BT_ / 128), 256, 0, stream>>>(
            h_bf, wqkv + (size_t)l * C3_ * C_, attn_b + l * C3_, nullptr, qkv_bf, BT_, C3_, C_);
        attn_mfma<<<dim3(768), 256, 0, stream>>>(
            qkv_bf, thr + l * H_, leak + l * H_, steep + l * H_, y_bf);
        gemm_mfma<0, 1, 0><<<dim3(C_ / 128, BT_ / 128), 256, 0, stream>>>(
            y_bf, wproj + (size_t)l * C_ * C_, proj_b + l * C_, x, x, BT_, C_, C_);
        ln_kernel<1><<<BT_, 256, 0, stream>>>(x, ln2_w + l * C_, ln2_b + l * C_, h_bf, 1, 0);
        gemm_mfma<1, 0, 1><<<dim3(C4_ / 128, BT_ / 128), 256, 0, stream>>>(
            h_bf, wfc + (size_t)l * C4_ * C_, fc_b + l * C4_, nullptr, m_bf, BT_, C4_, C_);
        gemm_mfma<0, 1, 0><<<dim3(C_ / 128, BT_ / 128), 256, 0, stream>>>(
            m_bf, wmproj + (size_t)l * C_ * C4_, mproj_b + l * C_, x, x, BT_, C_, C4_);
    }

    ln_kernel<0><<<8, 256, 0, stream>>>(x, lnf_w, lnf_b, xf, T_, T_ - 1);
    logits_kernel<<<(V_ + 3) / 4, 256, 0, stream>>>(xf, wte, out);
}